// Round 3
// baseline (574.746 us; speedup 1.0000x reference)
//
#include <hip/hip_runtime.h>
#include <hip/hip_bf16.h>
#include <math.h>

typedef unsigned short u16;
typedef short bf16x8 __attribute__((ext_vector_type(8)));
typedef float f32x4 __attribute__((ext_vector_type(4)));

#define LN2F 0.693147180559945f

__device__ __forceinline__ float bf2f(u16 h) {
  union { unsigned int i; float f; } v; v.i = ((unsigned int)h) << 16; return v.f;
}
__device__ __forceinline__ u16 f2bf(float f) {
  union { float f; unsigned int i; } v; v.f = f;
  unsigned int x = v.i;
  return (u16)((x + 0x7fffu + ((x >> 16) & 1u)) >> 16);
}
// shifted softplus via HW transcendentals (v_exp_f32 + v_log_f32).
// |err| <= ~2^-20 absolute vs log1pf version -- invisible at bf16 precision.
__device__ __forceinline__ float sspf(float v) {
  return fmaxf(v, 0.0f) + __logf(1.0f + __expf(-fabsf(v))) - LN2F;
}
template<int MODE>
__device__ __forceinline__ float ldv(const void* p, size_t i) {
  if constexpr (MODE == 0) return bf2f(((const u16*)p)[i]);
  else                     return ((const float*)p)[i];
}

// ---------------------------------------------------------------------------
// Dtype probe: bf16 N(0,1) data never has bf16-exponent >= 0xC0; f32 data
// misread as u16 halfwords certainly does.  0 = bf16 inputs, 1 = f32 inputs.
// ---------------------------------------------------------------------------
__global__ void probe_k(const u16* __restrict__ x, int* __restrict__ flag) {
  __shared__ int sf;
  if (threadIdx.x == 0) sf = 0;
  __syncthreads();
  int f = 0;
  for (int i = threadIdx.x; i < 4096; i += 256) {
    const unsigned e = (x[i] >> 7) & 0xFFu;
    if (e >= 0xC0u) f = 1;
  }
  if (f) atomicOr(&sf, 1);
  __syncthreads();
  if (threadIdx.x == 0) *flag = sf;
}

// ---------------------------------------------------------------------------
// Linear 16B-chunk copy (global -> LDS), 256 threads; conflict-free.
// ---------------------------------------------------------------------------
template<int NB>
__device__ __forceinline__ void copy_lin(const u16* __restrict__ g, u16* s, int tid) {
  constexpr int CH = NB / 16;
#pragma unroll
  for (int c = tid; c < CH; c += 256)
    *(bf16x8*)(s + (size_t)c * 8) = *(const bf16x8*)(g + (size_t)c * 8);
}

// 128x136 u16 weight buffer = 2176 16B chunks: reg-staged split (issue loads
// early, ds_write late -> HBM/L2 latency hides under activation VALU work).
__device__ __forceinline__ void wload(const u16* __restrict__ g, bf16x8* w, int tid) {
#pragma unroll
  for (int p = 0; p < 8; ++p) w[p] = *(const bf16x8*)(g + (size_t)(tid + p * 256) * 8);
  if (tid < 128) w[8] = *(const bf16x8*)(g + (size_t)(2048 + tid) * 8);
}
__device__ __forceinline__ void wstore(u16* s, const bf16x8* w, int tid) {
#pragma unroll
  for (int p = 0; p < 8; ++p) *(bf16x8*)(s + (size_t)(tid + p * 256) * 8) = w[p];
  if (tid < 128) *(bf16x8*)(s + (size_t)(2048 + tid) * 8) = w[8];
}

// MFMA sweep: acc[t] += sA_strip[m16][k] * sW[t*16+m16][k]
template<int KSTEPS, int LDW>
__device__ __forceinline__ void mm_lds(const u16* sA, const u16* sW, f32x4* acc,
                                       int m16, int quad) {
#pragma unroll
  for (int s = 0; s < KSTEPS; ++s) {
    const int k0 = s * 32 + quad * 8;
    bf16x8 a = *(const bf16x8*)(sA + (size_t)m16 * LDW + k0);
#pragma unroll
    for (int t = 0; t < 8; ++t) {
      bf16x8 b = *(const bf16x8*)(sW + (size_t)(t * 16 + m16) * LDW + k0);
      acc[t] = __builtin_amdgcn_mfma_f32_16x16x32_bf16(a, b, acc[t], 0, 0, 0);
    }
  }
}

// ---------------------------------------------------------------------------
// prep_k: transpose + bf16-convert every weight matrix ONCE into WT (padded).
// WT layout (u16 units): [0]=WiT [17408]=WjT [2*17408]=WfT
//   [ (3+l)*17408 ]   = Wr1T[l]   (each [128][136])
//   [ (3+L+l)*17408 ] = Wr2T[l]
//   [ (3+2L)*17408 ]  = Wk2fT    ([128][72])
// ---------------------------------------------------------------------------
template<int MODE>
__global__ __launch_bounds__(256) void prep_k(
    const int* __restrict__ mode,
    const void* __restrict__ Wi, const void* __restrict__ Wj,
    const void* __restrict__ Wf, const void* __restrict__ Wk2f,
    const void* __restrict__ Wr1, const void* __restrict__ Wr2,
    u16* __restrict__ WT, int L)
{
  if (*mode != MODE) return;
  const int b = blockIdx.x, tid = threadIdx.x;
  constexpr size_t esz = (MODE == 0) ? 2 : 4;
  const void* src; u16* dst; int KD = 128, LDW = 136;
  if      (b == 0) { src = Wi;  dst = WT; }
  else if (b == 1) { src = Wj;  dst = WT + 17408; }
  else if (b == 2) { src = Wf;  dst = WT + 2 * 17408; }
  else if (b == 3) { src = Wk2f; dst = WT + (size_t)(3 + 2 * L) * 17408; KD = 64; LDW = 72; }
  else if (b < 4 + L) { int l = b - 4;     src = (const char*)Wr1 + (size_t)l * 16384 * esz; dst = WT + (size_t)(3 + l) * 17408; }
  else                { int l = b - 4 - L; src = (const char*)Wr2 + (size_t)l * 16384 * esz; dst = WT + (size_t)(3 + L + l) * 17408; }

  const int n  = tid & 127;
  const int kh = (tid >> 7) * (KD >> 1);
  for (int c = 0; c < (KD >> 4); ++c) {
    const int k0 = kh + c * 8;
    bf16x8 rv;
#pragma unroll
    for (int j = 0; j < 8; ++j)
      rv[j] = (short)f2bf(ldv<MODE>(src, (size_t)(k0 + j) * 128 + n));
    *(bf16x8*)(dst + (size_t)n * LDW + k0) = rv;
  }
}

// ---------------------------------------------------------------------------
// in_k: fused xi/xj input GEMMs.  A = ssp(x) fragments held in regs once.
//   mb  = xi     = ssp(ssp(x)@Wi + bi)   [f32]
//   xjt = xj_all = ssp(ssp(x)@Wj + bj)   [bf16]
// Wj is reg-prefetched during the Wi MFMA sweep.
// ---------------------------------------------------------------------------
template<int MODE>
__global__ __launch_bounds__(256) void in_k(
    const int* __restrict__ mode, const void* __restrict__ x,
    const u16* __restrict__ WiT, const u16* __restrict__ WjT,
    const void* __restrict__ bi, const void* __restrict__ bj,
    float* __restrict__ mb, u16* __restrict__ xjt, int N)
{
  if (*mode != MODE) return;
  __shared__ u16 sW[128 * 136];
  const int tid = threadIdx.x, lane = tid & 63, wave = tid >> 6;
  const int m16 = lane & 15, quad = lane >> 4;
  const int row_tile = blockIdx.x * 64 + wave * 16;
  int arow = row_tile + m16; if (arow >= N) arow = N - 1;

  bf16x8 af[4];
#pragma unroll
  for (int s = 0; s < 4; ++s) {
    const int k0 = s * 32 + quad * 8;
    if constexpr (MODE == 0) {
      bf16x8 raw = *(const bf16x8*)((const u16*)x + (size_t)arow * 128 + k0);
#pragma unroll
      for (int j = 0; j < 8; ++j) af[s][j] = (short)f2bf(sspf(bf2f((u16)raw[j])));
    } else {
      const float* ap = (const float*)x + (size_t)arow * 128 + k0;
      float4 lo = *(const float4*)ap, hi = *(const float4*)(ap + 4);
      float v[8] = {lo.x, lo.y, lo.z, lo.w, hi.x, hi.y, hi.z, hi.w};
#pragma unroll
      for (int j = 0; j < 8; ++j) af[s][j] = (short)f2bf(sspf(v[j]));
    }
  }

  copy_lin<128 * 136 * 2>(WiT, sW, tid);
  __syncthreads();
  f32x4 aI[8], aJ[8];
#pragma unroll
  for (int t = 0; t < 8; ++t) aI[t] = (f32x4){0.f, 0.f, 0.f, 0.f};
  bf16x8 w[9];
  wload(WjT, w, tid);                 // prefetch Wj under the Wi sweep
#pragma unroll
  for (int s = 0; s < 4; ++s) {
    const int k0 = s * 32 + quad * 8;
#pragma unroll
    for (int t = 0; t < 8; ++t) {
      bf16x8 b = *(const bf16x8*)(sW + (size_t)(t * 16 + m16) * 136 + k0);
      aI[t] = __builtin_amdgcn_mfma_f32_16x16x32_bf16(af[s], b, aI[t], 0, 0, 0);
    }
  }
  __syncthreads();
  wstore(sW, w, tid);
  __syncthreads();
#pragma unroll
  for (int t = 0; t < 8; ++t) aJ[t] = (f32x4){0.f, 0.f, 0.f, 0.f};
#pragma unroll
  for (int s = 0; s < 4; ++s) {
    const int k0 = s * 32 + quad * 8;
#pragma unroll
    for (int t = 0; t < 8; ++t) {
      bf16x8 b = *(const bf16x8*)(sW + (size_t)(t * 16 + m16) * 136 + k0);
      aJ[t] = __builtin_amdgcn_mfma_f32_16x16x32_bf16(af[s], b, aJ[t], 0, 0, 0);
    }
  }

#pragma unroll
  for (int t = 0; t < 8; ++t) {
    const int col = t * 16 + m16;
    const float biv = ldv<MODE>(bi, col), bjv = ldv<MODE>(bj, col);
#pragma unroll
    for (int r = 0; r < 4; ++r) {
      const int ro = row_tile + quad * 4 + r;
      if (ro >= N) continue;
      const size_t off = (size_t)ro * 128 + col;
      mb[off]  = sspf(aI[t][r] + biv);
      xjt[off] = f2bf(sspf(aJ[t][r] + bjv));
    }
  }
}

// ---------------------------------------------------------------------------
// edge_k: persistent chunked blocks, 2-barrier/tile software pipeline.
// Each block owns a contiguous chunk of 64-edge tiles: sW (Wk2f^T) staged
// ONCE; per tile, the next tile's xj-gather / rbf / idx loads are issued into
// VGPRs before the current tile's scan (latency hides under scan + MFMA).
// Segment scan carries (node,sum) across tiles, flushing on node change only
// (any edge partition combines correctly via atomicAdd).
// LDS: sW 18432 + sXj 2x17408 + idx 1024 = 54272 B -> 3 blocks/CU.
// ---------------------------------------------------------------------------
template<int MODE>
__global__ __launch_bounds__(256) void edge_k(
    const int* __restrict__ mode,
    const void* __restrict__ rbf, const u16* __restrict__ WkT,
    const u16* __restrict__ xj_all, const int* __restrict__ idx_i,
    const int* __restrict__ idx_j, float* __restrict__ mb,
    int E, int ntiles, int chunk)
{
  if (*mode != MODE) return;
  __shared__ u16 sW[128 * 72];
  __shared__ u16 sXj[2][64 * 136];
  __shared__ int sIi[2][64], sIj[2][64];
  const int tid = threadIdx.x;
  const int tBeg = blockIdx.x * chunk;
  const int tEnd = min(tBeg + chunk, ntiles);
  if (tBeg >= ntiles) return;

  const int lane = tid & 63, wave = tid >> 6;
  const int m16 = lane & 15, quad = lane >> 4;
  const int gle = tid >> 4;            // gather row (+p*16)
  const int gc0 = (tid & 15) * 8;      // gather col chunk
  const int scol = tid & 127;          // scan column
  const int sbeg = (tid >> 7) * 32;    // scan row start

  bf16x8 rbH[2]; float4 rbF[4];        // rbf regs for one tile
  int ixi = -1, ixj = 0;               // idx regs for one tile (tid<64)

  auto loadRbf = [&](int tt) {
    int er = tt * 64 + wave * 16 + m16; if (er >= E) er = E - 1;
    if constexpr (MODE == 0) {
      const u16* p = (const u16*)rbf + (size_t)er * 64 + quad * 8;
      rbH[0] = *(const bf16x8*)p;
      rbH[1] = *(const bf16x8*)(p + 32);
    } else {
      const float* p = (const float*)rbf + (size_t)er * 64 + quad * 8;
      rbF[0] = *(const float4*)p;        rbF[1] = *(const float4*)(p + 4);
      rbF[2] = *(const float4*)(p + 32); rbF[3] = *(const float4*)(p + 36);
    }
  };
  auto loadIdx = [&](int tt) {
    if (tid < 64) {
      const int e = tt * 64 + tid;
      ixi = (e < E) ? idx_i[e] : -1;
      ixj = (e < E) ? idx_j[e] : 0;
    }
  };

  // prologue: weights once; tile tBeg gathered into sXj[0]; rbf+idx prefetched
  copy_lin<128 * 72 * 2>(WkT, sW, tid);
  loadIdx(tBeg);
  if (tid < 64) { sIi[0][tid] = ixi; sIj[0][tid] = ixj; }
  __syncthreads();
  bf16x8 g[4];
#pragma unroll
  for (int p = 0; p < 4; ++p)
    g[p] = *(const bf16x8*)(xj_all + (size_t)sIj[0][gle + p * 16] * 128 + gc0);
  loadRbf(tBeg);
  loadIdx(min(tBeg + 1, tEnd - 1));
#pragma unroll
  for (int p = 0; p < 4; ++p)
    *(bf16x8*)(&sXj[0][(size_t)(gle + p * 16) * 136 + gc0]) = g[p];

  int curNode = -1; float sum = 0.f;
  int cur = 0;
  for (int t = tBeg; t < tEnd; ++t, cur ^= 1) {
    const int nxt = cur ^ 1;
    __syncthreads();          // sXj[cur] gather + sI*[cur] visible
    // MFMA: g_tile = rbf @ Wk2f (A from regs, B from persistent sW)
    f32x4 acc[8];
#pragma unroll
    for (int t8 = 0; t8 < 8; ++t8) acc[t8] = (f32x4){0.f, 0.f, 0.f, 0.f};
#pragma unroll
    for (int s = 0; s < 2; ++s) {
      bf16x8 af;
      if constexpr (MODE == 0) af = rbH[s];
      else {
        const float4 lo = rbF[2 * s], hi = rbF[2 * s + 1];
        af[0] = f2bf(lo.x); af[1] = f2bf(lo.y); af[2] = f2bf(lo.z); af[3] = f2bf(lo.w);
        af[4] = f2bf(hi.x); af[5] = f2bf(hi.y); af[6] = f2bf(hi.z); af[7] = f2bf(hi.w);
      }
      const int k0 = s * 32 + quad * 8;
#pragma unroll
      for (int t8 = 0; t8 < 8; ++t8) {
        bf16x8 b = *(const bf16x8*)(sW + (size_t)(t8 * 16 + m16) * 72 + k0);
        acc[t8] = __builtin_amdgcn_mfma_f32_16x16x32_bf16(af, b, acc[t8], 0, 0, 0);
      }
    }
    if (tid < 64) { sIi[nxt][tid] = ixi; sIj[nxt][tid] = ixj; }
    // msg = g * xj, in place (each (le,col) slot owned by exactly one lane)
#pragma unroll
    for (int t8 = 0; t8 < 8; ++t8) {
      const int col = t8 * 16 + m16;
#pragma unroll
      for (int r = 0; r < 4; ++r) {
        const int le = wave * 16 + quad * 4 + r;
        const float xv = (t * 64 + le < E) ? bf2f(sXj[cur][(size_t)le * 136 + col]) : 0.f;
        sXj[cur][(size_t)le * 136 + col] = f2bf(acc[t8][r] * xv);
      }
    }
    __syncthreads();          // mult visible to scan; sIj[nxt] visible
    // issue next tile's loads (hide under scan)
    const bool more = (t + 1 < tEnd);
    if (more) {
#pragma unroll
      for (int p = 0; p < 4; ++p)
        g[p] = *(const bf16x8*)(xj_all + (size_t)sIj[nxt][gle + p * 16] * 128 + gc0);
      loadRbf(t + 1);
      loadIdx(min(t + 2, tEnd - 1));
    }
    // segment scan, carrying (node,sum) across tiles
#pragma unroll 4
    for (int r = 0; r < 32; ++r) {
      const int node = sIi[cur][sbeg + r];
      if (node != curNode) {
        if (curNode >= 0) atomicAdd(&mb[(size_t)curNode * 128 + scol], sum);
        sum = 0.f; curNode = node;
      }
      sum += bf2f(sXj[cur][(size_t)(sbeg + r) * 136 + scol]);
    }
    if (more) {
#pragma unroll
      for (int p = 0; p < 4; ++p)
        *(bf16x8*)(&sXj[nxt][(size_t)(gle + p * 16) * 136 + gc0]) = g[p];
    }
  }
  if (curNode >= 0) atomicAdd(&mb[(size_t)curNode * 128 + scol], sum);
}

// ---------------------------------------------------------------------------
// resid_k: fused residual chain + final output.  m stays in MFMA C-fragments.
// Per phase: issue next weight's global loads -> compute sM (ssp, VALU) ->
// ds_write weight -> barrier -> MFMA sweep.  Load latency hides under ssp.
// ---------------------------------------------------------------------------
template<int MODE>
__global__ __launch_bounds__(256) void resid_k(
    const int* __restrict__ mode, const float* __restrict__ mb,
    const u16* __restrict__ WT,
    const void* __restrict__ br1, const void* __restrict__ br2,
    const void* __restrict__ bfv, const void* __restrict__ x,
    const void* __restrict__ u, void* __restrict__ out, int N, int L)
{
  if (*mode != MODE) return;
  __shared__ u16 sW[128 * 136];
  __shared__ u16 sM[64 * 136];
  const int tid = threadIdx.x, lane = tid & 63, wave = tid >> 6;
  const int m16 = lane & 15, quad = lane >> 4;
  const int rbase = blockIdx.x * 64 + wave * 16 + quad * 4;
  u16* sMw = sM + (size_t)(wave * 16) * 136;   // wave's 16-row strip

  f32x4 m[8];
#pragma unroll
  for (int t = 0; t < 8; ++t) {
    const int col = t * 16 + m16;
#pragma unroll
    for (int r = 0; r < 4; ++r) {
      int ro = rbase + r; if (ro >= N) ro = N - 1;
      m[t][r] = mb[(size_t)ro * 128 + col];
    }
  }

  const u16* W1T = WT + (size_t)3 * 17408;
  const u16* W2T = WT + (size_t)(3 + L) * 17408;
  bf16x8 w[9];

  for (int l = 0; l < L; ++l) {
    // phase A: sM := ssp(m); sW := W1  (loads issued before the ssp block)
    wload(W1T + (size_t)l * 17408, w, tid);
#pragma unroll
    for (int t = 0; t < 8; ++t) {
      const int col = t * 16 + m16;
#pragma unroll
      for (int r = 0; r < 4; ++r)
        sM[(size_t)(wave * 16 + quad * 4 + r) * 136 + col] = f2bf(sspf(m[t][r]));
    }
    wstore(sW, w, tid);
    __syncthreads();

    f32x4 a1[8];
#pragma unroll
    for (int t = 0; t < 8; ++t) a1[t] = (f32x4){0.f, 0.f, 0.f, 0.f};
    mm_lds<4, 136>(sMw, sW, a1, m16, quad);
    __syncthreads();

    // phase B: sM := ssp(a1 + b1); sW := W2
    wload(W2T + (size_t)l * 17408, w, tid);
#pragma unroll
    for (int t = 0; t < 8; ++t) {
      const int col = t * 16 + m16;
      const float b1v = ldv<MODE>(br1, (size_t)l * 128 + col);
#pragma unroll
      for (int r = 0; r < 4; ++r)
        sM[(size_t)(wave * 16 + quad * 4 + r) * 136 + col] = f2bf(sspf(a1[t][r] + b1v));
    }
    wstore(sW, w, tid);
    __syncthreads();

    mm_lds<4, 136>(sMw, sW, m, m16, quad);   // m += t1 @ W2
#pragma unroll
    for (int t = 0; t < 8; ++t) {
      const float b2v = ldv<MODE>(br2, (size_t)l * 128 + t * 16 + m16);
#pragma unroll
      for (int r = 0; r < 4; ++r) m[t][r] += b2v;
    }
    __syncthreads();   // reads done before next phase's staging
  }

  // final: out = u*x + ssp(m)@Wf + bf
  wload(WT + (size_t)2 * 17408, w, tid);   // WfT
#pragma unroll
  for (int t = 0; t < 8; ++t) {
    const int col = t * 16 + m16;
#pragma unroll
    for (int r = 0; r < 4; ++r)
      sM[(size_t)(wave * 16 + quad * 4 + r) * 136 + col] = f2bf(sspf(m[t][r]));
  }
  wstore(sW, w, tid);
  __syncthreads();

  f32x4 o[8];
#pragma unroll
  for (int t = 0; t < 8; ++t) o[t] = (f32x4){0.f, 0.f, 0.f, 0.f};
  mm_lds<4, 136>(sMw, sW, o, m16, quad);

#pragma unroll
  for (int t = 0; t < 8; ++t) {
    const int col = t * 16 + m16;
    const float bv = ldv<MODE>(bfv, col), uvv = ldv<MODE>(u, col);
#pragma unroll
    for (int r = 0; r < 4; ++r) {
      const int ro = rbase + r;
      if (ro >= N) continue;
      const size_t off = (size_t)ro * 128 + col;
      const float ov = uvv * ldv<MODE>(x, off) + o[t][r] + bv;
      if constexpr (MODE == 0) ((u16*)out)[off] = f2bf(ov);
      else                     ((float*)out)[off] = ov;
    }
  }
}

// ---------------------------------------------------------------------------
template<int MODE>
static void run_pipeline(const int* flag,
                         const void* x, const void* rbf, const void* Wk2f,
                         const void* Wi, const void* bi, const void* Wj, const void* bj,
                         const void* Wr1, const void* br1, const void* Wr2, const void* br2,
                         const void* Wf, const void* bfv, const void* uv,
                         const int* idx_i, const int* idx_j,
                         u16* WT, float* mb, u16* xjt, void* out,
                         int N, int E, int L, hipStream_t stream)
{
  const dim3 blk(256);
  const int gridN = (N + 63) / 64;

  prep_k<MODE><<<4 + 2 * L, blk, 0, stream>>>(flag, Wi, Wj, Wf, Wk2f, Wr1, Wr2, WT, L);
  in_k<MODE><<<gridN, blk, 0, stream>>>(flag, x, WT, WT + 17408, bi, bj, mb, xjt, N);

  const int ntiles = (E + 63) >> 6;
  int nblk = ntiles < 768 ? ntiles : 768;        // ~3 persistent blocks/CU
  const int chunk = (ntiles + nblk - 1) / nblk;
  nblk = (ntiles + chunk - 1) / chunk;
  edge_k<MODE><<<nblk, blk, 0, stream>>>(flag, rbf, WT + (size_t)(3 + 2 * L) * 17408,
                                         xjt, idx_i, idx_j, mb, E, ntiles, chunk);

  resid_k<MODE><<<gridN, blk, 0, stream>>>(flag, mb, WT, br1, br2, bfv, x, uv, out, N, L);
}

extern "C" void kernel_launch(void* const* d_in, const int* in_sizes, int n_in,
                              void* d_out, int out_size, void* d_ws, size_t ws_size,
                              hipStream_t stream)
{
  const void* x    = d_in[0];
  const void* rbf  = d_in[1];
  const void* Wk2f = d_in[2];
  const void* Wi   = d_in[3];
  const void* bi   = d_in[4];
  const void* Wj   = d_in[5];
  const void* bj   = d_in[6];
  const void* Wr1  = d_in[7];
  const void* br1  = d_in[8];
  const void* Wr2  = d_in[9];
  const void* br2  = d_in[10];
  const void* Wf   = d_in[11];
  const void* bfv  = d_in[12];
  const void* uv   = d_in[13];
  const int* idx_i = (const int*)d_in[14];
  const int* idx_j = (const int*)d_in[15];

  const int N = in_sizes[0] / 128;
  const int E = in_sizes[14];
  const int L = in_sizes[7] / (128 * 128);

  int* flag = (int*)d_ws;
  char* wsb = (char*)d_ws + 16;
  const size_t avail = ws_size > 16 ? ws_size - 16 : 0;

  // pre-transposed weight area (bf16, padded strides)
  const size_t needW  = ((size_t)(3 + 2 * L) * 17408 + 9216) * 2;
  const size_t needWA = (needW + 255) & ~(size_t)255;
  u16* WT = (u16*)wsb;
  char* wsb2 = wsb + needWA;
  const size_t avail2 = (avail > needWA) ? avail - needWA : 0;

  const size_t needF = (size_t)N * 512;   // mb f32
  const size_t needH = (size_t)N * 256;   // xj_all bf16

  // bf16-mode layout
  float* mb0; u16* xjt0;
  if (avail2 >= needF + needH) { mb0 = (float*)wsb2; xjt0 = (u16*)(wsb2 + needF); }
  else                         { mb0 = (float*)wsb2; xjt0 = (u16*)d_out; }
  // f32-mode layout (d_out is N*128 f32 -> can host mb in-place; resid reads
  // its own rows before writing them, so mb==out is safe)
  float* mb1; u16* xjt1;
  if (avail2 >= needF + needH)      { mb1 = (float*)wsb2;  xjt1 = (u16*)(wsb2 + needF); }
  else if (avail2 >= needF)         { mb1 = (float*)wsb2;  xjt1 = (u16*)d_out; }
  else                              { mb1 = (float*)d_out; xjt1 = (u16*)wsb2; }

  probe_k<<<1, 256, 0, stream>>>((const u16*)x, flag);
  run_pipeline<0>(flag, x, rbf, Wk2f, Wi, bi, Wj, bj, Wr1, br1, Wr2, br2,
                  Wf, bfv, uv, idx_i, idx_j, WT, mb0, xjt0, d_out, N, E, L, stream);
  run_pipeline<1>(flag, x, rbf, Wk2f, Wi, bi, Wj, bj, Wr1, br1, Wr2, br2,
                  Wf, bfv, uv, idx_i, idx_j, WT, mb1, xjt1, d_out, N, E, L, stream);
}

// Round 4
// 510.600 us; speedup vs baseline: 1.1256x; 1.1256x over previous
//
#include <hip/hip_runtime.h>
#include <hip/hip_bf16.h>
#include <math.h>

typedef unsigned short u16;
typedef short bf16x8 __attribute__((ext_vector_type(8)));
typedef float f32x4 __attribute__((ext_vector_type(4)));

#define LN2F 0.693147180559945f

__device__ __forceinline__ float bf2f(u16 h) {
  union { unsigned int i; float f; } v; v.i = ((unsigned int)h) << 16; return v.f;
}
__device__ __forceinline__ u16 f2bf(float f) {
  union { float f; unsigned int i; } v; v.f = f;
  unsigned int x = v.i;
  return (u16)((x + 0x7fffu + ((x >> 16) & 1u)) >> 16);
}
// shifted softplus via HW transcendentals (v_exp_f32 + v_log_f32).
// |err| <= ~2^-20 absolute vs log1pf version -- invisible at bf16 precision.
__device__ __forceinline__ float sspf(float v) {
  return fmaxf(v, 0.0f) + __logf(1.0f + __expf(-fabsf(v))) - LN2F;
}
template<int MODE>
__device__ __forceinline__ float ldv(const void* p, size_t i) {
  if constexpr (MODE == 0) return bf2f(((const u16*)p)[i]);
  else                     return ((const float*)p)[i];
}

// ---------------------------------------------------------------------------
// Dtype probe: bf16 N(0,1) data never has bf16-exponent >= 0xC0; f32 data
// misread as u16 halfwords certainly does.  0 = bf16 inputs, 1 = f32 inputs.
// ---------------------------------------------------------------------------
__global__ void probe_k(const u16* __restrict__ x, int* __restrict__ flag) {
  __shared__ int sf;
  if (threadIdx.x == 0) sf = 0;
  __syncthreads();
  int f = 0;
  for (int i = threadIdx.x; i < 4096; i += 256) {
    const unsigned e = (x[i] >> 7) & 0xFFu;
    if (e >= 0xC0u) f = 1;
  }
  if (f) atomicOr(&sf, 1);
  __syncthreads();
  if (threadIdx.x == 0) *flag = sf;
}

// ---------------------------------------------------------------------------
// Linear 16B-chunk copy (global -> LDS), 256 threads; conflict-free.
// ---------------------------------------------------------------------------
template<int NB>
__device__ __forceinline__ void copy_lin(const u16* __restrict__ g, u16* s, int tid) {
  constexpr int CH = NB / 16;
#pragma unroll
  for (int c = tid; c < CH; c += 256)
    *(bf16x8*)(s + (size_t)c * 8) = *(const bf16x8*)(g + (size_t)c * 8);
}

// 128x136 u16 weight buffer = 2176 16B chunks: reg-staged split (issue loads
// early, ds_write late -> HBM/L2 latency hides under activation VALU work).
__device__ __forceinline__ void wload(const u16* __restrict__ g, bf16x8* w, int tid) {
#pragma unroll
  for (int p = 0; p < 8; ++p) w[p] = *(const bf16x8*)(g + (size_t)(tid + p * 256) * 8);
  if (tid < 128) w[8] = *(const bf16x8*)(g + (size_t)(2048 + tid) * 8);
}
__device__ __forceinline__ void wstore(u16* s, const bf16x8* w, int tid) {
#pragma unroll
  for (int p = 0; p < 8; ++p) *(bf16x8*)(s + (size_t)(tid + p * 256) * 8) = w[p];
  if (tid < 128) *(bf16x8*)(s + (size_t)(2048 + tid) * 8) = w[8];
}

// MFMA sweep: acc[t] += sA_strip[m16][k] * sW[t*16+m16][k]
template<int KSTEPS, int LDW>
__device__ __forceinline__ void mm_lds(const u16* sA, const u16* sW, f32x4* acc,
                                       int m16, int quad) {
#pragma unroll
  for (int s = 0; s < KSTEPS; ++s) {
    const int k0 = s * 32 + quad * 8;
    bf16x8 a = *(const bf16x8*)(sA + (size_t)m16 * LDW + k0);
#pragma unroll
    for (int t = 0; t < 8; ++t) {
      bf16x8 b = *(const bf16x8*)(sW + (size_t)(t * 16 + m16) * LDW + k0);
      acc[t] = __builtin_amdgcn_mfma_f32_16x16x32_bf16(a, b, acc[t], 0, 0, 0);
    }
  }
}

// ---------------------------------------------------------------------------
// prep_k: transpose + bf16-convert every weight matrix ONCE into WT (padded).
// WT layout (u16 units): [0]=WiT [17408]=WjT [2*17408]=WfT
//   [ (3+l)*17408 ]   = Wr1T[l]   (each [128][136])
//   [ (3+L+l)*17408 ] = Wr2T[l]
//   [ (3+2L)*17408 ]  = Wk2fT    ([128][72])
// ---------------------------------------------------------------------------
template<int MODE>
__global__ __launch_bounds__(256) void prep_k(
    const int* __restrict__ mode,
    const void* __restrict__ Wi, const void* __restrict__ Wj,
    const void* __restrict__ Wf, const void* __restrict__ Wk2f,
    const void* __restrict__ Wr1, const void* __restrict__ Wr2,
    u16* __restrict__ WT, int L)
{
  if (*mode != MODE) return;
  const int b = blockIdx.x, tid = threadIdx.x;
  constexpr size_t esz = (MODE == 0) ? 2 : 4;
  const void* src; u16* dst; int KD = 128, LDW = 136;
  if      (b == 0) { src = Wi;  dst = WT; }
  else if (b == 1) { src = Wj;  dst = WT + 17408; }
  else if (b == 2) { src = Wf;  dst = WT + 2 * 17408; }
  else if (b == 3) { src = Wk2f; dst = WT + (size_t)(3 + 2 * L) * 17408; KD = 64; LDW = 72; }
  else if (b < 4 + L) { int l = b - 4;     src = (const char*)Wr1 + (size_t)l * 16384 * esz; dst = WT + (size_t)(3 + l) * 17408; }
  else                { int l = b - 4 - L; src = (const char*)Wr2 + (size_t)l * 16384 * esz; dst = WT + (size_t)(3 + L + l) * 17408; }

  const int n  = tid & 127;
  const int kh = (tid >> 7) * (KD >> 1);
  for (int c = 0; c < (KD >> 4); ++c) {
    const int k0 = kh + c * 8;
    bf16x8 rv;
#pragma unroll
    for (int j = 0; j < 8; ++j)
      rv[j] = (short)f2bf(ldv<MODE>(src, (size_t)(k0 + j) * 128 + n));
    *(bf16x8*)(dst + (size_t)n * LDW + k0) = rv;
  }
}

// ---------------------------------------------------------------------------
// in_k: fused xi/xj input GEMMs.  A = ssp(x) fragments held in regs once.
//   mb  = xi     = ssp(ssp(x)@Wi + bi)   [f32]
//   xjt = xj_all = ssp(ssp(x)@Wj + bj)   [bf16]
// Wj is reg-prefetched during the Wi MFMA sweep.
// ---------------------------------------------------------------------------
template<int MODE>
__global__ __launch_bounds__(256) void in_k(
    const int* __restrict__ mode, const void* __restrict__ x,
    const u16* __restrict__ WiT, const u16* __restrict__ WjT,
    const void* __restrict__ bi, const void* __restrict__ bj,
    float* __restrict__ mb, u16* __restrict__ xjt, int N)
{
  if (*mode != MODE) return;
  __shared__ u16 sW[128 * 136];
  const int tid = threadIdx.x, lane = tid & 63, wave = tid >> 6;
  const int m16 = lane & 15, quad = lane >> 4;
  const int row_tile = blockIdx.x * 64 + wave * 16;
  int arow = row_tile + m16; if (arow >= N) arow = N - 1;

  bf16x8 af[4];
#pragma unroll
  for (int s = 0; s < 4; ++s) {
    const int k0 = s * 32 + quad * 8;
    if constexpr (MODE == 0) {
      bf16x8 raw = *(const bf16x8*)((const u16*)x + (size_t)arow * 128 + k0);
#pragma unroll
      for (int j = 0; j < 8; ++j) af[s][j] = (short)f2bf(sspf(bf2f((u16)raw[j])));
    } else {
      const float* ap = (const float*)x + (size_t)arow * 128 + k0;
      float4 lo = *(const float4*)ap, hi = *(const float4*)(ap + 4);
      float v[8] = {lo.x, lo.y, lo.z, lo.w, hi.x, hi.y, hi.z, hi.w};
#pragma unroll
      for (int j = 0; j < 8; ++j) af[s][j] = (short)f2bf(sspf(v[j]));
    }
  }

  copy_lin<128 * 136 * 2>(WiT, sW, tid);
  __syncthreads();
  f32x4 aI[8], aJ[8];
#pragma unroll
  for (int t = 0; t < 8; ++t) aI[t] = (f32x4){0.f, 0.f, 0.f, 0.f};
  bf16x8 w[9];
  wload(WjT, w, tid);                 // prefetch Wj under the Wi sweep
#pragma unroll
  for (int s = 0; s < 4; ++s) {
    const int k0 = s * 32 + quad * 8;
#pragma unroll
    for (int t = 0; t < 8; ++t) {
      bf16x8 b = *(const bf16x8*)(sW + (size_t)(t * 16 + m16) * 136 + k0);
      aI[t] = __builtin_amdgcn_mfma_f32_16x16x32_bf16(af[s], b, aI[t], 0, 0, 0);
    }
  }
  __syncthreads();
  wstore(sW, w, tid);
  __syncthreads();
#pragma unroll
  for (int t = 0; t < 8; ++t) aJ[t] = (f32x4){0.f, 0.f, 0.f, 0.f};
#pragma unroll
  for (int s = 0; s < 4; ++s) {
    const int k0 = s * 32 + quad * 8;
#pragma unroll
    for (int t = 0; t < 8; ++t) {
      bf16x8 b = *(const bf16x8*)(sW + (size_t)(t * 16 + m16) * 136 + k0);
      aJ[t] = __builtin_amdgcn_mfma_f32_16x16x32_bf16(af[s], b, aJ[t], 0, 0, 0);
    }
  }

#pragma unroll
  for (int t = 0; t < 8; ++t) {
    const int col = t * 16 + m16;
    const float biv = ldv<MODE>(bi, col), bjv = ldv<MODE>(bj, col);
#pragma unroll
    for (int r = 0; r < 4; ++r) {
      const int ro = row_tile + quad * 4 + r;
      if (ro >= N) continue;
      const size_t off = (size_t)ro * 128 + col;
      mb[off]  = sspf(aI[t][r] + biv);
      xjt[off] = f2bf(sspf(aJ[t][r] + bjv));
    }
  }
}

// ---------------------------------------------------------------------------
// edge_k: one 64-edge tile per block (12500 blocks -> max TLP).  ALL global
// loads issued up-front before the first barrier (weights reg-staged, rbf in
// regs, idx_j direct from global, xj gathered DIRECTLY in MFMA C-fragment
// layout as 32x2B loads from the L2/L3-hot xj table) -> ~45 outstanding
// loads/wave for latency hiding.  msg = g*xj computed in registers; only the
// scan transpose goes through LDS.  2 barriers per block (was 3).
// LDS: sW 18432 + sMsg 16896 + sIi 256 = 35584 B -> 4 blocks/CU.
// ---------------------------------------------------------------------------
template<int MODE>
__global__ __launch_bounds__(256) void edge_k(
    const int* __restrict__ mode,
    const void* __restrict__ rbf, const u16* __restrict__ WkT,
    const u16* __restrict__ xj_all, const int* __restrict__ idx_i,
    const int* __restrict__ idx_j, float* __restrict__ mb, int E)
{
  if (*mode != MODE) return;
  __shared__ u16 sW[128 * 72];
  __shared__ u16 sMsg[64][132];
  __shared__ int sIi[64];
  const int tid = threadIdx.x;
  const int e0 = blockIdx.x * 64;
  const int lane = tid & 63, wave = tid >> 6;
  const int m16 = lane & 15, quad = lane >> 4;
  const int lebase = wave * 16 + quad * 4;   // this lane's 4 owned edge rows

  // idx_i for the scan (LDS); idx_j for owned rows straight from global
  if (tid < 64) sIi[tid] = (e0 + tid < E) ? idx_i[e0 + tid] : -1;
  int jrow[4];
#pragma unroll
  for (int r = 0; r < 4; ++r) {
    const int e = e0 + lebase + r;
    jrow[r] = (e < E) ? idx_j[e] : 0;        // broadcast-cached 4B loads
  }

  // weight stage into regs (18432 B = 1152 x 16B chunks; issue early)
  bf16x8 w[5];
#pragma unroll
  for (int p = 0; p < 4; ++p) w[p] = *(const bf16x8*)(WkT + (size_t)(tid + p * 256) * 8);
  if (tid < 128) w[4] = *(const bf16x8*)(WkT + (size_t)(1024 + tid) * 8);

  // rbf A-fragments into regs
  int er = e0 + wave * 16 + m16; if (er >= E) er = E - 1;
  bf16x8 rbH[2]; float4 rbF[4];
  if constexpr (MODE == 0) {
    const u16* p = (const u16*)rbf + (size_t)er * 64 + quad * 8;
    rbH[0] = *(const bf16x8*)p;
    rbH[1] = *(const bf16x8*)(p + 32);
  } else {
    const float* p = (const float*)rbf + (size_t)er * 64 + quad * 8;
    rbF[0] = *(const float4*)p;        rbF[1] = *(const float4*)(p + 4);
    rbF[2] = *(const float4*)(p + 32); rbF[3] = *(const float4*)(p + 36);
  }

  // gather xj directly in C-fragment layout (32 x 2B per lane, L2/L3-hot)
  u16 xg[8][4];
#pragma unroll
  for (int r = 0; r < 4; ++r) {
    const u16* xr = xj_all + (size_t)jrow[r] * 128 + m16;
#pragma unroll
    for (int t = 0; t < 8; ++t) xg[t][r] = xr[t * 16];
  }

  // commit weights to LDS (waits only on the weight loads), barrier
#pragma unroll
  for (int p = 0; p < 4; ++p) *(bf16x8*)(sW + (size_t)(tid + p * 256) * 8) = w[p];
  if (tid < 128) *(bf16x8*)(sW + (size_t)(1024 + tid) * 8) = w[4];
  __syncthreads();

  // MFMA: g = rbf @ Wk2f
  f32x4 acc[8];
#pragma unroll
  for (int t = 0; t < 8; ++t) acc[t] = (f32x4){0.f, 0.f, 0.f, 0.f};
#pragma unroll
  for (int s = 0; s < 2; ++s) {
    bf16x8 af;
    if constexpr (MODE == 0) af = rbH[s];
    else {
      const float4 lo = rbF[2 * s], hi = rbF[2 * s + 1];
      af[0] = f2bf(lo.x); af[1] = f2bf(lo.y); af[2] = f2bf(lo.z); af[3] = f2bf(lo.w);
      af[4] = f2bf(hi.x); af[5] = f2bf(hi.y); af[6] = f2bf(hi.z); af[7] = f2bf(hi.w);
    }
    const int k0 = s * 32 + quad * 8;
#pragma unroll
    for (int t = 0; t < 8; ++t) {
      bf16x8 b = *(const bf16x8*)(sW + (size_t)(t * 16 + m16) * 72 + k0);
      acc[t] = __builtin_amdgcn_mfma_f32_16x16x32_bf16(af, b, acc[t], 0, 0, 0);
    }
  }

  // msg = g * xj in registers; write owner slots to sMsg for the scan
#pragma unroll
  for (int t = 0; t < 8; ++t) {
    const int col = t * 16 + m16;
#pragma unroll
    for (int r = 0; r < 4; ++r) {
      const float xvf = (e0 + lebase + r < E) ? bf2f(xg[t][r]) : 0.f;
      sMsg[lebase + r][col] = f2bf(acc[t][r] * xvf);
    }
  }
  __syncthreads();

  // segment scan over sorted idx_i; boundary atomics
  const int scol = tid & 127;
  const int sbeg = (tid >> 7) * 32;
  float sum = 0.f;
  int cur = sIi[sbeg];
#pragma unroll 4
  for (int r = 0; r < 32; ++r) {
    const int node = sIi[sbeg + r];
    if (node != cur) {
      if (cur >= 0) atomicAdd(&mb[(size_t)cur * 128 + scol], sum);
      sum = 0.f; cur = node;
    }
    sum += bf2f(sMsg[sbeg + r][scol]);
  }
  if (cur >= 0) atomicAdd(&mb[(size_t)cur * 128 + scol], sum);
}

// ---------------------------------------------------------------------------
// resid_k: fused residual chain + final output.  m stays in MFMA C-fragments.
// Per phase: issue next weight's global loads -> compute sM (ssp, VALU) ->
// ds_write weight -> barrier -> MFMA sweep.  Load latency hides under ssp.
// ---------------------------------------------------------------------------
template<int MODE>
__global__ __launch_bounds__(256) void resid_k(
    const int* __restrict__ mode, const float* __restrict__ mb,
    const u16* __restrict__ WT,
    const void* __restrict__ br1, const void* __restrict__ br2,
    const void* __restrict__ bfv, const void* __restrict__ x,
    const void* __restrict__ u, void* __restrict__ out, int N, int L)
{
  if (*mode != MODE) return;
  __shared__ u16 sW[128 * 136];
  __shared__ u16 sM[64 * 136];
  const int tid = threadIdx.x, lane = tid & 63, wave = tid >> 6;
  const int m16 = lane & 15, quad = lane >> 4;
  const int rbase = blockIdx.x * 64 + wave * 16 + quad * 4;
  u16* sMw = sM + (size_t)(wave * 16) * 136;   // wave's 16-row strip

  f32x4 m[8];
#pragma unroll
  for (int t = 0; t < 8; ++t) {
    const int col = t * 16 + m16;
#pragma unroll
    for (int r = 0; r < 4; ++r) {
      int ro = rbase + r; if (ro >= N) ro = N - 1;
      m[t][r] = mb[(size_t)ro * 128 + col];
    }
  }

  const u16* W1T = WT + (size_t)3 * 17408;
  const u16* W2T = WT + (size_t)(3 + L) * 17408;
  bf16x8 w[9];

  for (int l = 0; l < L; ++l) {
    // phase A: sM := ssp(m); sW := W1  (loads issued before the ssp block)
    wload(W1T + (size_t)l * 17408, w, tid);
#pragma unroll
    for (int t = 0; t < 8; ++t) {
      const int col = t * 16 + m16;
#pragma unroll
      for (int r = 0; r < 4; ++r)
        sM[(size_t)(wave * 16 + quad * 4 + r) * 136 + col] = f2bf(sspf(m[t][r]));
    }
    wstore(sW, w, tid);
    __syncthreads();

    f32x4 a1[8];
#pragma unroll
    for (int t = 0; t < 8; ++t) a1[t] = (f32x4){0.f, 0.f, 0.f, 0.f};
    mm_lds<4, 136>(sMw, sW, a1, m16, quad);
    __syncthreads();

    // phase B: sM := ssp(a1 + b1); sW := W2
    wload(W2T + (size_t)l * 17408, w, tid);
#pragma unroll
    for (int t = 0; t < 8; ++t) {
      const int col = t * 16 + m16;
      const float b1v = ldv<MODE>(br1, (size_t)l * 128 + col);
#pragma unroll
      for (int r = 0; r < 4; ++r)
        sM[(size_t)(wave * 16 + quad * 4 + r) * 136 + col] = f2bf(sspf(a1[t][r] + b1v));
    }
    wstore(sW, w, tid);
    __syncthreads();

    mm_lds<4, 136>(sMw, sW, m, m16, quad);   // m += t1 @ W2
#pragma unroll
    for (int t = 0; t < 8; ++t) {
      const float b2v = ldv<MODE>(br2, (size_t)l * 128 + t * 16 + m16);
#pragma unroll
      for (int r = 0; r < 4; ++r) m[t][r] += b2v;
    }
    __syncthreads();   // reads done before next phase's staging
  }

  // final: out = u*x + ssp(m)@Wf + bf
  wload(WT + (size_t)2 * 17408, w, tid);   // WfT
#pragma unroll
  for (int t = 0; t < 8; ++t) {
    const int col = t * 16 + m16;
#pragma unroll
    for (int r = 0; r < 4; ++r)
      sM[(size_t)(wave * 16 + quad * 4 + r) * 136 + col] = f2bf(sspf(m[t][r]));
  }
  wstore(sW, w, tid);
  __syncthreads();

  f32x4 o[8];
#pragma unroll
  for (int t = 0; t < 8; ++t) o[t] = (f32x4){0.f, 0.f, 0.f, 0.f};
  mm_lds<4, 136>(sMw, sW, o, m16, quad);

#pragma unroll
  for (int t = 0; t < 8; ++t) {
    const int col = t * 16 + m16;
    const float bv = ldv<MODE>(bfv, col), uvv = ldv<MODE>(u, col);
#pragma unroll
    for (int r = 0; r < 4; ++r) {
      const int ro = rbase + r;
      if (ro >= N) continue;
      const size_t off = (size_t)ro * 128 + col;
      const float ov = uvv * ldv<MODE>(x, off) + o[t][r] + bv;
      if constexpr (MODE == 0) ((u16*)out)[off] = f2bf(ov);
      else                     ((float*)out)[off] = ov;
    }
  }
}

// ---------------------------------------------------------------------------
template<int MODE>
static void run_pipeline(const int* flag,
                         const void* x, const void* rbf, const void* Wk2f,
                         const void* Wi, const void* bi, const void* Wj, const void* bj,
                         const void* Wr1, const void* br1, const void* Wr2, const void* br2,
                         const void* Wf, const void* bfv, const void* uv,
                         const int* idx_i, const int* idx_j,
                         u16* WT, float* mb, u16* xjt, void* out,
                         int N, int E, int L, hipStream_t stream)
{
  const dim3 blk(256);
  const int gridN = (N + 63) / 64;
  const int gridE = (E + 63) / 64;

  prep_k<MODE><<<4 + 2 * L, blk, 0, stream>>>(flag, Wi, Wj, Wf, Wk2f, Wr1, Wr2, WT, L);
  in_k<MODE><<<gridN, blk, 0, stream>>>(flag, x, WT, WT + 17408, bi, bj, mb, xjt, N);
  edge_k<MODE><<<gridE, blk, 0, stream>>>(flag, rbf, WT + (size_t)(3 + 2 * L) * 17408,
                                          xjt, idx_i, idx_j, mb, E);
  resid_k<MODE><<<gridN, blk, 0, stream>>>(flag, mb, WT, br1, br2, bfv, x, uv, out, N, L);
}

extern "C" void kernel_launch(void* const* d_in, const int* in_sizes, int n_in,
                              void* d_out, int out_size, void* d_ws, size_t ws_size,
                              hipStream_t stream)
{
  const void* x    = d_in[0];
  const void* rbf  = d_in[1];
  const void* Wk2f = d_in[2];
  const void* Wi   = d_in[3];
  const void* bi   = d_in[4];
  const void* Wj   = d_in[5];
  const void* bj   = d_in[6];
  const void* Wr1  = d_in[7];
  const void* br1  = d_in[8];
  const void* Wr2  = d_in[9];
  const void* br2  = d_in[10];
  const void* Wf   = d_in[11];
  const void* bfv  = d_in[12];
  const void* uv   = d_in[13];
  const int* idx_i = (const int*)d_in[14];
  const int* idx_j = (const int*)d_in[15];

  const int N = in_sizes[0] / 128;
  const int E = in_sizes[14];
  const int L = in_sizes[7] / (128 * 128);

  int* flag = (int*)d_ws;
  char* wsb = (char*)d_ws + 16;
  const size_t avail = ws_size > 16 ? ws_size - 16 : 0;

  // pre-transposed weight area (bf16, padded strides)
  const size_t needW  = ((size_t)(3 + 2 * L) * 17408 + 9216) * 2;
  const size_t needWA = (needW + 255) & ~(size_t)255;
  u16* WT = (u16*)wsb;
  char* wsb2 = wsb + needWA;
  const size_t avail2 = (avail > needWA) ? avail - needWA : 0;

  const size_t needF = (size_t)N * 512;   // mb f32
  const size_t needH = (size_t)N * 256;   // xj_all bf16

  // bf16-mode layout
  float* mb0; u16* xjt0;
  if (avail2 >= needF + needH) { mb0 = (float*)wsb2; xjt0 = (u16*)(wsb2 + needF); }
  else                         { mb0 = (float*)wsb2; xjt0 = (u16*)d_out; }
  // f32-mode layout (d_out is N*128 f32 -> can host mb in-place; resid reads
  // its own rows before writing them, so mb==out is safe)
  float* mb1; u16* xjt1;
  if (avail2 >= needF + needH)      { mb1 = (float*)wsb2;  xjt1 = (u16*)(wsb2 + needF); }
  else if (avail2 >= needF)         { mb1 = (float*)wsb2;  xjt1 = (u16*)d_out; }
  else                              { mb1 = (float*)d_out; xjt1 = (u16*)wsb2; }

  probe_k<<<1, 256, 0, stream>>>((const u16*)x, flag);
  run_pipeline<0>(flag, x, rbf, Wk2f, Wi, bi, Wj, bj, Wr1, br1, Wr2, br2,
                  Wf, bfv, uv, idx_i, idx_j, WT, mb0, xjt0, d_out, N, E, L, stream);
  run_pipeline<1>(flag, x, rbf, Wk2f, Wi, bi, Wj, bj, Wr1, br1, Wr2, br2,
                  Wf, bfv, uv, idx_i, idx_j, WT, mb1, xjt1, d_out, N, E, L, stream);
}